// Round 6
// baseline (113.074 us; speedup 1.0000x reference)
//
#include <hip/hip_runtime.h>
#include <stdint.h>

// HamiltonianFlow: x [256, 8, 32, 2] (q,p); H = 0.5*sum(p^2) + MLP(q).
// dq/dt = p, dp/dt = -W u(z), z = W^T q + b1, u = (1-tanh^2(z)).*W2.
// z-space iteration with M = W^T W (R15-R23 verified).
//
// R29b = R29 (8-step exchanges) with LDS ducked under the 160KiB cap.
// R29's only identified launch risk was LDS == 163840 B (exactly max).
// Fix: hoist the epilogue W-fragment (wBt) into registers right after the
// M-build (+32 VGPR), after which wldsT is DEAD -> ubuf aliases the first
// 32768 B of wldsT. mscr (live during M-build) stays separate.
// Total LDS = 131072 + 20480 = 151552 B (< all previously-verified sizes).
//
// R29 design: R26/R27/R28 (three different structures) all measured
// 46-49us => cost is per-exchange and structural (~4500 cyc: barrier
// convergence + LDS round-trip + MFMA-chain + reduction latency),
// nearly independent of interior arrangement. Lever: fewer exchanges.
// Per barrier: TWO 16-row A-tiles (tile0 = steps 0-3, tile1 = steps 4-7,
// rows 4*step+stage), TWO MFMA blocks (same wM B-frags, 4 indep chains),
// exact 8-step advance:
//   z += 8dt*P - dtdt6*SV8;  P -= dt6*SB8
//   SB8 = sum B_j;  SV8 = sum (7-j)B_j + sum A_j
// Lane owns steps j1=quad (tile0 C) and j2=quad+4 (tile1 C):
//   V = A1 + A2 + (3-quad)*(B1+B2) + 4*B1;  2 bfly4 per 8 steps.
// Prediction (R25-verified proxy, horizon 8): for step j,
//   Pp  = P - (j/8)*dt6*SBp
//   zp2 = 2z + 2j*dt*P + dtdt6*j(8-j)/8 * SBp - dtdt6*j/4 * SVp   [2z form]
// own-step stage lags Y1L/Y2L now lag-8. Proxy err ~1e-5-class stage-z,
// >=6x under the f16 u-rounding floor. 100 = 12x8 + 4: tail exchange
// reuses tile0 with the H=4 reconstruction. 13 barriers instead of 25.
//
// ubuf swizzle (both arrays share it): idx(row,k) = row*256 +
// (k ^ ((row&7)<<3)) [16B-granular involution]. Read addressing folds to
// 2 base regs + ds imm offsets (bit-5 via +-swhi even/odd-kk bases).
// ONE barrier per exchange (R24 double-buffer race argument unchanged).
// FULL unroll on every reg-array access (R4: dynamic index => scratch).
// Numerics: f16 storage (W, M, u, S), fp32 MFMA accum + fp32 z/P state.

typedef _Float16 v8h __attribute__((ext_vector_type(8)));
typedef float v4f __attribute__((ext_vector_type(4)));

#define NFULL 12   // full 8-step exchanges; + 1 tail exchange of 4 steps

// D(+=C) in VGPRs, A (packed-vector frag) in VGPRs, B (M-frag) from AGPRs.
#define MFMA_AV(C, A, B) \
    asm("v_mfma_f32_16x16x32_f16 %0, %1, %2, %0" : "+v"(C) : "v"(A), "a"(B))

// 4-group butterfly sum over lanes {l, l^16, l^32, l^48}, pure VALU.
__device__ __forceinline__ float bfly4(float x) {
    float a = x, b = x;
    asm("v_permlane16_swap_b32 %0, %1" : "+v"(a), "+v"(b));
    float s = a + b;
    float c = s, d = s;
    asm("v_permlane32_swap_b32 %0, %1" : "+v"(c), "+v"(d));
    return c + d;
}

// u/(4*w2) eval on pre-doubled arg zz = 2*z:  r = rcp(e^zz + 1);
// u = 4*w2*(r - r^2)  ==  (1 - tanh^2(z)) * w2  exactly in algebra.
__device__ __forceinline__ float ueval2(float zz, float w4) {
    float e_ = __expf(zz);
    float r_ = __builtin_amdgcn_rcpf(e_ + 1.f);   // vs IEEE div: ~1e-7 rel
    return w4 * __builtin_fmaf(-r_, r_, r_);
}

__global__ __launch_bounds__(1024, 4)
void ham_kernel(const float* __restrict__ x0, const float* __restrict__ W1,
                const float* __restrict__ b1, const float* __restrict__ W2,
                float* __restrict__ out)
{
    __shared__ __align__(128) _Float16 wldsT[256 * 256];  // 131072 B, swizzled
    __shared__ __align__(16)  float    mscr[16 * 320];    // 20480 B, M-build
    _Float16* ubuf = wldsT;   // ALIAS: wldsT dead after wBt hoist + barrier
                              // ubuf = 2 x 32 rows x 256 f16 (rows 0..63)

    const int t = threadIdx.x;
    const int w = t >> 6;          // wave 0..15: owns tile w (16 comps)
    const int l = t & 63;
    const int quad = l >> 4;       // step slot: j1=quad, j2=quad+4
    const int s = l & 15;          // owned column / A-row
    const int c0 = 16 * w + s;     // owned component
    const int blk = blockIdx.x;
    const int kq = 8 * quad;

    // ---- stage W^T -> LDS f16 swizzled: idx = c*256 + (k ^ ((c&7)<<3)) ----
    {
        const int c = t & 255;
        const int rbase = (t >> 8) * 64;   // 4 quarters x 64 k-rows
        const int csw = (c & 7) << 3;
        #pragma unroll 1
        for (int r0 = 0; r0 < 64; r0 += 8) {
            v8h h;
            #pragma unroll
            for (int j = 0; j < 8; ++j)
                h[j] = (_Float16)W1[(rbase + r0 + j) * 256 + c];
            *(v8h*)(wldsT + c * 256 + ((rbase + r0) ^ csw)) = h;  // one chunk
        }
    }
    __syncthreads();

    // ---- wF: own-column W^T frag (B-op), swizzled chunk reads ----
    v8h wF0[8];
    const int c0sw = (c0 & 7) << 3;
    #pragma unroll
    for (int kk = 0; kk < 8; ++kk)
        wF0[kk] = *(const v8h*)(wldsT + c0 * 256 + ((32 * kk + kq) ^ c0sw));

    // ---- build M = W^T W column-block frags wM0 (B-op: M[k][c0]) ----
    v8h wM0[8];
    float* scr0 = mscr + w * 320;
    const int ssw = (s & 7) << 3;
    #pragma unroll
    for (int kb = 0; kb < 16; ++kb) {
        v8h aM[8];   // A[m=s][k] = W[k][16kb+s], swizzled row 16kb+s
        #pragma unroll
        for (int kk = 0; kk < 8; ++kk)
            aM[kk] = *(const v8h*)(wldsT + (16 * kb + s) * 256
                                          + ((32 * kk + kq) ^ ssw));
        v4f D0 = {0.f,0.f,0.f,0.f};
        #pragma unroll
        for (int kk = 0; kk < 8; ++kk)
            D0 = __builtin_amdgcn_mfma_f32_16x16x32_f16(aM[kk], wF0[kk], D0, 0, 0, 0);
        *(v4f*)(scr0 + s * 20 + 4 * quad) = D0;
        asm volatile("s_waitcnt lgkmcnt(0)" ::: "memory");  // in-wave x-lane
        if ((quad >> 1) == (kb & 1)) {
            #pragma unroll
            for (int j = 0; j < 8; ++j)
                wM0[kb >> 1][j] = (_Float16)scr0[s * 20 + 8 * (quad & 1) + j];
        }
        asm volatile("s_waitcnt lgkmcnt(0)" ::: "memory");
    }

    // ---- hoist epilogue W-frag into regs (then wldsT is DEAD) ----
    // wBt[kk][j] = W[c0][32kk+kq+j] = wldsT[32kk+kq+j][c0]; (row&7)==j
    v8h wBt0[8];
    #pragma unroll
    for (int kk = 0; kk < 8; ++kk)
        #pragma unroll
        for (int j = 0; j < 8; ++j)
            wBt0[kk][j] = wldsT[(32 * kk + kq + j) * 256 + (c0 ^ (j << 3))];
    __syncthreads();   // all waves done reading wldsT/mscr -> ubuf may reuse

    const float b1r0 = b1[c0];
    const float w4 = 4.f * W2[c0];
    float2 qp0 = ((const float2*)(x0 + (size_t)blk * 512))[c0];
    const float q0o0 = qp0.x, p0o0 = qp0.y;

    // ---- prologue: buf0 rows {q0, p0, 0, 0} -> z1 (C[0]), P (C[1]) ----
    if (quad == 0) {
        ubuf[0 * 256 + (c0 ^ 0)]  = (_Float16)q0o0;
        ubuf[1 * 256 + (c0 ^ 8)]  = (_Float16)p0o0;
        ubuf[2 * 256 + (c0 ^ 16)] = (_Float16)0.f;
        ubuf[3 * 256 + (c0 ^ 24)] = (_Float16)0.f;
    }
    __syncthreads();
    float z1, P;
    {
        const int rowp = s & 3;    // rows 0-3: XOR folds to quad^rowp
        const _Float16* ab = ubuf + rowp * 256 + 8 * (quad ^ rowp);
        v4f C0a = {0.f,0.f,0.f,0.f}, C0b = {0.f,0.f,0.f,0.f};
        #pragma unroll
        for (int kk = 0; kk < 8; kk += 2) {
            v8h a0 = *(const v8h*)(ab + 32 * kk);
            v8h a1 = *(const v8h*)(ab + 32 * (kk + 1));
            C0a = __builtin_amdgcn_mfma_f32_16x16x32_f16(a0, wF0[kk], C0a, 0, 0, 0);
            C0b = __builtin_amdgcn_mfma_f32_16x16x32_f16(a1, wF0[kk + 1], C0b, 0, 0, 0);
        }
        v4f C0s = C0a + C0b;
        z1 = C0s[0] + b1r0;  P = C0s[1];
    }
    __syncthreads();   // prologue reads done before u(0) overwrites buf0

    const float dt = 0.01f, hdt = 0.005f, dt6 = 0.01f / 6.f;
    const float dtdt6 = dt * dt6, hdt2 = hdt * hdt, dthdt = dt * hdt;
    const float K8dt = 8.f * dt, K4dt = 4.f * dt;
    // per-step-j prediction coefs (horizon-8 proxy), j1=quad, j2=quad+4
    const float qf1 = (float)quad, qf2 = qf1 + 4.f;
    const float cPn1 = -(qf1 * 0.125f * dt6), cPn2 = -(qf2 * 0.125f * dt6);
    const float Kz1a = 2.f * qf1 * dt,        Kz1b = 2.f * qf2 * dt;
    const float KB1 = dtdt6 * qf1 * (8.f - qf1) * 0.125f;
    const float KB2 = dtdt6 * qf2 * (8.f - qf2) * 0.125f;
    const float KVn1 = -(qf1 * dtdt6 * 0.25f), KVn2 = -(qf2 * dtdt6 * 0.25f);
    const float K2hdt = 2.f * hdt, K2hdt2n = -2.f * hdt2;
    const float K2dt = 2.f * dt,   K2dthdtn = -2.f * dthdt;
    const float w3q = 3.f - qf1;   // (3-quad): V weight, and tail (3-j)

    // ---- ubuf addressing (swizzle folded to bases + imm offsets) ----
    // reads: row s (tile1 at +4096), logical chunk (32kk+kq) ^ ((s&7)<<3):
    //   bits3-4 fold into base; bit5 (+-swhi) splits even/odd kk bases.
    const int swhi = (s & 4) << 3;
    const int pbase = s * 256 + (kq ^ ((s & 3) << 3));
    const int beven = pbase + swhi;
    const int bodd  = pbase - swhi;
    // writes: row R = 4*quad+st, col c0: R*256 + (c0 ^ ((R&7)<<3));
    // tile1 at +4096 (same XOR: (16+R)&7 == R&7). Constant per lane.
    const int R0 = 4 * quad;
    const int wo0 = (R0 + 0) * 256 + (c0 ^ (((R0 + 0) & 7) << 3));
    const int wo1 = (R0 + 1) * 256 + (c0 ^ (((R0 + 1) & 7) << 3));
    const int wo2 = (R0 + 2) * 256 + (c0 ^ (((R0 + 2) & 7) << 3));
    const int wo3 = (R0 + 3) * 256 + (c0 ^ (((R0 + 3) & 7) << 3));

    // lag state (previous exchange's sums / own-slot Ys; exchange 0: zeros
    // -> one-time transient, same benign class as R25, err ~4e-5 stage-z)
    float SBp = 0.f, SVp = 0.f;
    float Y1L1 = 0.f, Y2L1 = 0.f, Y1L2 = 0.f, Y2L2 = 0.f;
    float S1p = 0.f, S23p = 0.f;
    float cn = 99.f - qf1;

    #pragma unroll 1
    for (int e = 0; e < NFULL; ++e) {
        const int bo = (e & 1) << 13;   // double-buffer offset (8192 f16)

        // ---- produce u for steps j1, j2 (8 evals); write both tiles ----
        float z1d = z1 + z1;
        float Pp1 = __builtin_fmaf(cPn1, SBp, P);
        float zp21 = __builtin_fmaf(Kz1a, P, z1d);
        zp21 = __builtin_fmaf(KB1, SBp, zp21);
        zp21 = __builtin_fmaf(KVn1, SVp, zp21);
        float zb21 = __builtin_fmaf(K2hdt, Pp1, zp21);
        float zc21 = __builtin_fmaf(K2hdt2n, Y1L1, zb21);
        float zd21 = __builtin_fmaf(K2dt, Pp1, zp21);
        zd21 = __builtin_fmaf(K2dthdtn, Y2L1, zd21);
        float Pp2 = __builtin_fmaf(cPn2, SBp, P);
        float zp22 = __builtin_fmaf(Kz1b, P, z1d);
        zp22 = __builtin_fmaf(KB2, SBp, zp22);
        zp22 = __builtin_fmaf(KVn2, SVp, zp22);
        float zb22 = __builtin_fmaf(K2hdt, Pp2, zp22);
        float zc22 = __builtin_fmaf(K2hdt2n, Y1L2, zb22);
        float zd22 = __builtin_fmaf(K2dt, Pp2, zp22);
        zd22 = __builtin_fmaf(K2dthdtn, Y2L2, zd22);

        float ua1 = ueval2(zp21, w4), ub1 = ueval2(zb21, w4);
        float uc1 = ueval2(zc21, w4), ud1 = ueval2(zd21, w4);
        float ua2 = ueval2(zp22, w4), ub2 = ueval2(zb22, w4);
        float uc2 = ueval2(zc22, w4), ud2 = ueval2(zd22, w4);

        ubuf[bo + wo0] = (_Float16)ua1;  ubuf[bo + wo0 + 4096] = (_Float16)ua2;
        ubuf[bo + wo1] = (_Float16)ub1;  ubuf[bo + wo1 + 4096] = (_Float16)ub2;
        ubuf[bo + wo2] = (_Float16)uc1;  ubuf[bo + wo2 + 4096] = (_Float16)uc2;
        ubuf[bo + wo3] = (_Float16)ud1;  ubuf[bo + wo3 + 4096] = (_Float16)ud2;
        __syncthreads();   // the ONLY barrier per exchange (8 steps)

        // ---- TWO MFMA blocks (tile0 -> j1 Ys, tile1 -> j2 Ys) ----
        v4f C0a = {0.f,0.f,0.f,0.f}, C0b = {0.f,0.f,0.f,0.f};
        v4f C1a = {0.f,0.f,0.f,0.f}, C1b = {0.f,0.f,0.f,0.f};
        {
            const _Float16* pe = ubuf + bo + beven;
            const _Float16* po = ubuf + bo + bodd;
            #pragma unroll
            for (int kk = 0; kk < 8; kk += 2) {
                v8h a00 = *(const v8h*)(pe + 32 * kk);
                v8h a01 = *(const v8h*)(po + 32 * (kk + 1));
                v8h a10 = *(const v8h*)(pe + 32 * kk + 4096);
                v8h a11 = *(const v8h*)(po + 32 * (kk + 1) + 4096);
                MFMA_AV(C0a, a00, wM0[kk]);
                MFMA_AV(C1a, a10, wM0[kk]);
                MFMA_AV(C0b, a01, wM0[kk + 1]);
                MFMA_AV(C1b, a11, wM0[kk + 1]);
            }
        }
        // no second barrier: next exchange writes the OTHER buffer (R24).

        // ---- combos, 2 butterflies, EXACT 8-step advance ----
        v4f C0 = C0a + C0b, C1 = C1a + C1b;
        float Y11 = C0[0], Y21 = C0[1], Y31 = C0[2], Y41 = C0[3];
        float Y12 = C1[0], Y22 = C1[1], Y32 = C1[2], Y42 = C1[3];
        float tA1 = Y21 + Y31, A1 = Y11 + tA1, B1 = A1 + tA1 + Y41;
        float tA2 = Y22 + Y32, A2 = Y12 + tA2, B2 = A2 + tA2 + Y42;
        float Bs = B1 + B2;
        float V = __builtin_fmaf(w3q, Bs, A1 + A2);
        V = __builtin_fmaf(4.f, B1, V);        // (7-j1)B1+(3-q)B2+A1+A2
        float SB = bfly4(Bs);
        float SV = bfly4(V);

        z1 = __builtin_fmaf(K8dt, P, z1);      // z += 8dt*P (old P)
        z1 = __builtin_fmaf(-dtdt6, SV, z1);
        P  = __builtin_fmaf(-dt6, SB, P);

        SBp = SB;  SVp = SV;                   // lag sums
        Y1L1 = Y11; Y2L1 = Y21; Y1L2 = Y12; Y2L2 = Y22;

        // ---- S partials: steps n1 = 8e+quad, n2 = n1+4 ----
        float tv1 = ub1 + uc1, sp1 = __builtin_fmaf(2.f, tv1, ua1 + ud1);
        float sq1 = ua1 + tv1;
        float tv2 = ub2 + uc2, sp2 = __builtin_fmaf(2.f, tv2, ua2 + ud2);
        float sq2 = ua2 + tv2;
        S1p += sp1 + sp2;
        S23p = __builtin_fmaf(cn, sp1, S23p) + sq1;
        S23p = __builtin_fmaf(cn - 4.f, sp2, S23p) + sq2;
        cn -= 8.f;
    }

    // ---- tail exchange: steps 96-99, buf0, tile0 only (H=4 exact) ----
    {
        float z1d = z1 + z1;
        float Pp1 = __builtin_fmaf(cPn1, SBp, P);
        float zp21 = __builtin_fmaf(Kz1a, P, z1d);
        zp21 = __builtin_fmaf(KB1, SBp, zp21);
        zp21 = __builtin_fmaf(KVn1, SVp, zp21);
        float zb21 = __builtin_fmaf(K2hdt, Pp1, zp21);
        float zc21 = __builtin_fmaf(K2hdt2n, Y1L1, zb21);
        float zd21 = __builtin_fmaf(K2dt, Pp1, zp21);
        zd21 = __builtin_fmaf(K2dthdtn, Y2L1, zd21);
        float ua1 = ueval2(zp21, w4), ub1 = ueval2(zb21, w4);
        float uc1 = ueval2(zc21, w4), ud1 = ueval2(zd21, w4);
        ubuf[wo0] = (_Float16)ua1;  ubuf[wo1] = (_Float16)ub1;
        ubuf[wo2] = (_Float16)uc1;  ubuf[wo3] = (_Float16)ud1;
        __syncthreads();

        v4f C0a = {0.f,0.f,0.f,0.f}, C0b = {0.f,0.f,0.f,0.f};
        {
            const _Float16* pe = ubuf + beven;
            const _Float16* po = ubuf + bodd;
            #pragma unroll
            for (int kk = 0; kk < 8; kk += 2) {
                v8h a00 = *(const v8h*)(pe + 32 * kk);
                v8h a01 = *(const v8h*)(po + 32 * (kk + 1));
                MFMA_AV(C0a, a00, wM0[kk]);
                MFMA_AV(C0b, a01, wM0[kk + 1]);
            }
        }
        v4f C0 = C0a + C0b;
        float Y11 = C0[0], Y21 = C0[1], Y31 = C0[2], Y41 = C0[3];
        float tA1 = Y21 + Y31, A1 = Y11 + tA1, B1 = A1 + tA1 + Y41;
        float V = __builtin_fmaf(w3q, B1, A1);   // H=4: (3-j)B + A
        float SB = bfly4(B1);
        float SV = bfly4(V);
        z1 = __builtin_fmaf(K4dt, P, z1);
        z1 = __builtin_fmaf(-dtdt6, SV, z1);
        P  = __builtin_fmaf(-dt6, SB, P);
        float tv1 = ub1 + uc1, sp1 = __builtin_fmaf(2.f, tv1, ua1 + ud1);
        float sq1 = ua1 + tv1;
        S1p += sp1;
        S23p = __builtin_fmaf(cn, sp1, S23p) + sq1;   // cn = 3-quad here
    }

    // ---- epilogue: reduce S; buf0 rows {S1, S23, 0, 0}; final MFMA ----
    const float S1f  = bfly4(S1p);
    const float S23f = bfly4(S23p);
    __syncthreads();   // tail's buf0 reads done before overwrite
    if (quad == 0) {
        ubuf[0 * 256 + (c0 ^ 0)]  = (_Float16)S1f;
        ubuf[1 * 256 + (c0 ^ 8)]  = (_Float16)S23f;
        ubuf[2 * 256 + (c0 ^ 16)] = (_Float16)0.f;
        ubuf[3 * 256 + (c0 ^ 24)] = (_Float16)0.f;
    }
    __syncthreads();
    float D10, D20;
    {
        const int rowp = s & 3;
        const _Float16* ab = ubuf + rowp * 256 + 8 * (quad ^ rowp);
        v4f C0a = {0.f,0.f,0.f,0.f}, C0b = {0.f,0.f,0.f,0.f};
        #pragma unroll
        for (int kk = 0; kk < 8; kk += 2) {
            v8h a0 = *(const v8h*)(ab + 32 * kk);
            v8h a1 = *(const v8h*)(ab + 32 * (kk + 1));
            C0a = __builtin_amdgcn_mfma_f32_16x16x32_f16(a0, wBt0[kk], C0a, 0, 0, 0);
            C0b = __builtin_amdgcn_mfma_f32_16x16x32_f16(a1, wBt0[kk + 1], C0b, 0, 0, 0);
        }
        v4f C0s = C0a + C0b;
        D10 = C0s[0];  D20 = C0s[1];
    }
    const float dt6e = 0.01f / 6.f, dtdt6e = 0.01f * dt6e;
    float pT0 = p0o0 - dt6e * D10;
    float qT0 = q0o0 + 0.01f * 100.f * p0o0 - dtdt6e * D20;

    if (quad == 0)
        ((float2*)(out + (size_t)blk * 512))[c0] = make_float2(qT0, pT0);
}

extern "C" void kernel_launch(void* const* d_in, const int* in_sizes, int n_in,
                              void* d_out, int out_size, void* d_ws, size_t ws_size,
                              hipStream_t stream) {
    const float* x0 = (const float*)d_in[0];
    const float* W1 = (const float*)d_in[1];
    const float* b1 = (const float*)d_in[2];
    const float* W2 = (const float*)d_in[3];
    // d_in[4] = b2: constant offset, no effect on the gradient/dynamics.
    float* out = (float*)d_out;
    hipLaunchKernelGGL(ham_kernel, dim3(256), dim3(1024), 0, stream,
                       x0, W1, b1, W2, out);
}

// Round 7
// 106.100 us; speedup vs baseline: 1.0657x; 1.0657x over previous
//
#include <hip/hip_runtime.h>
#include <stdint.h>

// HamiltonianFlow: x [256, 8, 32, 2] (q,p); H = 0.5*sum(p^2) + MLP(q).
// dq/dt = p, dp/dt = -W u(z), z = W^T q + b1, u = (1-tanh^2(z)).*W2.
// z-space iteration with M = W^T W (R15-R23 verified).
//
// R29c = R29b minus the register-spill bug. R29b's counters: FETCH 23MB /
// WRITE 46MB / 1.15TB/s => the wBt0 hoist (+32 VGPR live across the whole
// loop) spilled ~178KB/block to scratch; the kernel went memory-bound on
// its own spill traffic (61us ~ 70MB/1.15TB/s). Fix: NO hoist. The
// epilogue B-frag is wBt[kk][j] = W[c0][32kk+kq+j] = W1[c0*256+32kk+kq+j]
// -- contiguous in j in GLOBAL memory -> load it in the epilogue as
// 2 x float4 per kk (W1 is L2/L3-hot by then), convert f32->f16 (same
// conversion as staging => bit-identical). wldsT stays dead after the
// M-build barrier (wF0 in regs), so ubuf still aliases wldsT.
// LDS = 131072 + 20480 = 151552 B.
//
// R29 design (numerics verified by R29b's bit-identical absmax):
// 8-STEP EXCHANGES. R26/R27/R28 (three different structures) all measured
// 46-49us => cost is per-exchange and structural (~4500 cyc: barrier
// convergence + LDS round-trip + MFMA-chain + reduction latency).
// Lever: fewer exchanges. Per barrier: TWO 16-row A-tiles (tile0 = steps
// 0-3, tile1 = steps 4-7, rows 4*step+stage), TWO MFMA blocks (same wM
// B-frags, 4 indep accumulator chains), exact 8-step advance:
//   z += 8dt*P - dtdt6*SV8;  P -= dt6*SB8
//   SB8 = sum B_j;  SV8 = sum (7-j)B_j + sum A_j
// Lane owns steps j1=quad (tile0 C) and j2=quad+4 (tile1 C):
//   V = A1 + A2 + (3-quad)*(B1+B2) + 4*B1;  2 bfly4 per 8 steps.
// Prediction (horizon-8 proxy): for step j,
//   Pp  = P - (j/8)*dt6*SBp
//   zp2 = 2z + 2j*dt*P + dtdt6*j(8-j)/8 * SBp - dtdt6*j/4 * SVp   [2z form]
// own-step stage lags Y1L/Y2L lag-8. 100 = 12x8 + 4: tail exchange
// reuses tile0 with the H=4 reconstruction. 13 barriers instead of 25.
//
// ubuf swizzle (shared with wldsT): idx(row,k) = row*256 +
// (k ^ ((row&7)<<3)) [16B-granular involution]. Read addressing folds to
// 2 base regs + ds imm offsets (bit-5 via +-swhi even/odd-kk bases).
// ONE barrier per exchange (R24 double-buffer race argument unchanged).
// FULL unroll on every reg-array access (R4: dynamic index => scratch).
// Numerics: f16 storage (W, M, u, S), fp32 MFMA accum + fp32 z/P state.

typedef _Float16 v8h __attribute__((ext_vector_type(8)));
typedef float v4f __attribute__((ext_vector_type(4)));

#define NFULL 12   // full 8-step exchanges; + 1 tail exchange of 4 steps

// D(+=C) in VGPRs, A (packed-vector frag) in VGPRs, B (M-frag) from AGPRs.
#define MFMA_AV(C, A, B) \
    asm("v_mfma_f32_16x16x32_f16 %0, %1, %2, %0" : "+v"(C) : "v"(A), "a"(B))

// 4-group butterfly sum over lanes {l, l^16, l^32, l^48}, pure VALU.
__device__ __forceinline__ float bfly4(float x) {
    float a = x, b = x;
    asm("v_permlane16_swap_b32 %0, %1" : "+v"(a), "+v"(b));
    float s = a + b;
    float c = s, d = s;
    asm("v_permlane32_swap_b32 %0, %1" : "+v"(c), "+v"(d));
    return c + d;
}

// u/(4*w2) eval on pre-doubled arg zz = 2*z:  r = rcp(e^zz + 1);
// u = 4*w2*(r - r^2)  ==  (1 - tanh^2(z)) * w2  exactly in algebra.
__device__ __forceinline__ float ueval2(float zz, float w4) {
    float e_ = __expf(zz);
    float r_ = __builtin_amdgcn_rcpf(e_ + 1.f);   // vs IEEE div: ~1e-7 rel
    return w4 * __builtin_fmaf(-r_, r_, r_);
}

__global__ __launch_bounds__(1024, 4)
void ham_kernel(const float* __restrict__ x0, const float* __restrict__ W1,
                const float* __restrict__ b1, const float* __restrict__ W2,
                float* __restrict__ out)
{
    __shared__ __align__(128) _Float16 wldsT[256 * 256];  // 131072 B, swizzled
    __shared__ __align__(16)  float    mscr[16 * 320];    // 20480 B, M-build
    _Float16* ubuf = wldsT;   // ALIAS: wldsT dead after M-build barrier
                              // ubuf = 2 x 32 rows x 256 f16 (rows 0..63)

    const int t = threadIdx.x;
    const int w = t >> 6;          // wave 0..15: owns tile w (16 comps)
    const int l = t & 63;
    const int quad = l >> 4;       // step slot: j1=quad, j2=quad+4
    const int s = l & 15;          // owned column / A-row
    const int c0 = 16 * w + s;     // owned component
    const int blk = blockIdx.x;
    const int kq = 8 * quad;

    // ---- stage W^T -> LDS f16 swizzled: idx = c*256 + (k ^ ((c&7)<<3)) ----
    {
        const int c = t & 255;
        const int rbase = (t >> 8) * 64;   // 4 quarters x 64 k-rows
        const int csw = (c & 7) << 3;
        #pragma unroll 1
        for (int r0 = 0; r0 < 64; r0 += 8) {
            v8h h;
            #pragma unroll
            for (int j = 0; j < 8; ++j)
                h[j] = (_Float16)W1[(rbase + r0 + j) * 256 + c];
            *(v8h*)(wldsT + c * 256 + ((rbase + r0) ^ csw)) = h;  // one chunk
        }
    }
    __syncthreads();

    // ---- wF: own-column W^T frag (B-op), swizzled chunk reads ----
    v8h wF0[8];
    const int c0sw = (c0 & 7) << 3;
    #pragma unroll
    for (int kk = 0; kk < 8; ++kk)
        wF0[kk] = *(const v8h*)(wldsT + c0 * 256 + ((32 * kk + kq) ^ c0sw));

    // ---- build M = W^T W column-block frags wM0 (B-op: M[k][c0]) ----
    v8h wM0[8];
    float* scr0 = mscr + w * 320;
    const int ssw = (s & 7) << 3;
    #pragma unroll
    for (int kb = 0; kb < 16; ++kb) {
        v8h aM[8];   // A[m=s][k] = W[k][16kb+s], swizzled row 16kb+s
        #pragma unroll
        for (int kk = 0; kk < 8; ++kk)
            aM[kk] = *(const v8h*)(wldsT + (16 * kb + s) * 256
                                          + ((32 * kk + kq) ^ ssw));
        v4f D0 = {0.f,0.f,0.f,0.f};
        #pragma unroll
        for (int kk = 0; kk < 8; ++kk)
            D0 = __builtin_amdgcn_mfma_f32_16x16x32_f16(aM[kk], wF0[kk], D0, 0, 0, 0);
        *(v4f*)(scr0 + s * 20 + 4 * quad) = D0;
        asm volatile("s_waitcnt lgkmcnt(0)" ::: "memory");  // in-wave x-lane
        if ((quad >> 1) == (kb & 1)) {
            #pragma unroll
            for (int j = 0; j < 8; ++j)
                wM0[kb >> 1][j] = (_Float16)scr0[s * 20 + 8 * (quad & 1) + j];
        }
        asm volatile("s_waitcnt lgkmcnt(0)" ::: "memory");
    }
    __syncthreads();   // all waves done reading wldsT/mscr -> ubuf may reuse

    const float b1r0 = b1[c0];
    const float w4 = 4.f * W2[c0];
    float2 qp0 = ((const float2*)(x0 + (size_t)blk * 512))[c0];
    const float q0o0 = qp0.x, p0o0 = qp0.y;

    // ---- prologue: buf0 rows {q0, p0, 0, 0} -> z1 (C[0]), P (C[1]) ----
    if (quad == 0) {
        ubuf[0 * 256 + (c0 ^ 0)]  = (_Float16)q0o0;
        ubuf[1 * 256 + (c0 ^ 8)]  = (_Float16)p0o0;
        ubuf[2 * 256 + (c0 ^ 16)] = (_Float16)0.f;
        ubuf[3 * 256 + (c0 ^ 24)] = (_Float16)0.f;
    }
    __syncthreads();
    float z1, P;
    {
        const int rowp = s & 3;    // rows 0-3: XOR folds to quad^rowp
        const _Float16* ab = ubuf + rowp * 256 + 8 * (quad ^ rowp);
        v4f C0a = {0.f,0.f,0.f,0.f}, C0b = {0.f,0.f,0.f,0.f};
        #pragma unroll
        for (int kk = 0; kk < 8; kk += 2) {
            v8h a0 = *(const v8h*)(ab + 32 * kk);
            v8h a1 = *(const v8h*)(ab + 32 * (kk + 1));
            C0a = __builtin_amdgcn_mfma_f32_16x16x32_f16(a0, wF0[kk], C0a, 0, 0, 0);
            C0b = __builtin_amdgcn_mfma_f32_16x16x32_f16(a1, wF0[kk + 1], C0b, 0, 0, 0);
        }
        v4f C0s = C0a + C0b;
        z1 = C0s[0] + b1r0;  P = C0s[1];
    }
    __syncthreads();   // prologue reads done before u(0) overwrites buf0

    const float dt = 0.01f, hdt = 0.005f, dt6 = 0.01f / 6.f;
    const float dtdt6 = dt * dt6, hdt2 = hdt * hdt, dthdt = dt * hdt;
    const float K8dt = 8.f * dt, K4dt = 4.f * dt;
    // per-step-j prediction coefs (horizon-8 proxy), j1=quad, j2=quad+4
    const float qf1 = (float)quad, qf2 = qf1 + 4.f;
    const float cPn1 = -(qf1 * 0.125f * dt6), cPn2 = -(qf2 * 0.125f * dt6);
    const float Kz1a = 2.f * qf1 * dt,        Kz1b = 2.f * qf2 * dt;
    const float KB1 = dtdt6 * qf1 * (8.f - qf1) * 0.125f;
    const float KB2 = dtdt6 * qf2 * (8.f - qf2) * 0.125f;
    const float KVn1 = -(qf1 * dtdt6 * 0.25f), KVn2 = -(qf2 * dtdt6 * 0.25f);
    const float K2hdt = 2.f * hdt, K2hdt2n = -2.f * hdt2;
    const float K2dt = 2.f * dt,   K2dthdtn = -2.f * dthdt;
    const float w3q = 3.f - qf1;   // (3-quad): V weight, and tail (3-j)

    // ---- ubuf addressing (swizzle folded to bases + imm offsets) ----
    // reads: row s (tile1 at +4096), logical chunk (32kk+kq) ^ ((s&7)<<3):
    //   bits3-4 fold into base; bit5 (+-swhi) splits even/odd kk bases.
    const int swhi = (s & 4) << 3;
    const int pbase = s * 256 + (kq ^ ((s & 3) << 3));
    const int beven = pbase + swhi;
    const int bodd  = pbase - swhi;
    // writes: row R = 4*quad+st, col c0: R*256 + (c0 ^ ((R&7)<<3));
    // tile1 at +4096 (same XOR: (16+R)&7 == R&7). Constant per lane.
    const int R0 = 4 * quad;
    const int wo0 = (R0 + 0) * 256 + (c0 ^ (((R0 + 0) & 7) << 3));
    const int wo1 = (R0 + 1) * 256 + (c0 ^ (((R0 + 1) & 7) << 3));
    const int wo2 = (R0 + 2) * 256 + (c0 ^ (((R0 + 2) & 7) << 3));
    const int wo3 = (R0 + 3) * 256 + (c0 ^ (((R0 + 3) & 7) << 3));

    // lag state (previous exchange's sums / own-slot Ys; exchange 0: zeros
    // -> one-time transient, same benign class as R25, err ~4e-5 stage-z)
    float SBp = 0.f, SVp = 0.f;
    float Y1L1 = 0.f, Y2L1 = 0.f, Y1L2 = 0.f, Y2L2 = 0.f;
    float S1p = 0.f, S23p = 0.f;
    float cn = 99.f - qf1;

    #pragma unroll 1
    for (int e = 0; e < NFULL; ++e) {
        const int bo = (e & 1) << 13;   // double-buffer offset (8192 f16)

        // ---- produce u for steps j1, j2 (8 evals); write both tiles ----
        float z1d = z1 + z1;
        float Pp1 = __builtin_fmaf(cPn1, SBp, P);
        float zp21 = __builtin_fmaf(Kz1a, P, z1d);
        zp21 = __builtin_fmaf(KB1, SBp, zp21);
        zp21 = __builtin_fmaf(KVn1, SVp, zp21);
        float zb21 = __builtin_fmaf(K2hdt, Pp1, zp21);
        float zc21 = __builtin_fmaf(K2hdt2n, Y1L1, zb21);
        float zd21 = __builtin_fmaf(K2dt, Pp1, zp21);
        zd21 = __builtin_fmaf(K2dthdtn, Y2L1, zd21);
        float Pp2 = __builtin_fmaf(cPn2, SBp, P);
        float zp22 = __builtin_fmaf(Kz1b, P, z1d);
        zp22 = __builtin_fmaf(KB2, SBp, zp22);
        zp22 = __builtin_fmaf(KVn2, SVp, zp22);
        float zb22 = __builtin_fmaf(K2hdt, Pp2, zp22);
        float zc22 = __builtin_fmaf(K2hdt2n, Y1L2, zb22);
        float zd22 = __builtin_fmaf(K2dt, Pp2, zp22);
        zd22 = __builtin_fmaf(K2dthdtn, Y2L2, zd22);

        float ua1 = ueval2(zp21, w4), ub1 = ueval2(zb21, w4);
        float uc1 = ueval2(zc21, w4), ud1 = ueval2(zd21, w4);
        float ua2 = ueval2(zp22, w4), ub2 = ueval2(zb22, w4);
        float uc2 = ueval2(zc22, w4), ud2 = ueval2(zd22, w4);

        ubuf[bo + wo0] = (_Float16)ua1;  ubuf[bo + wo0 + 4096] = (_Float16)ua2;
        ubuf[bo + wo1] = (_Float16)ub1;  ubuf[bo + wo1 + 4096] = (_Float16)ub2;
        ubuf[bo + wo2] = (_Float16)uc1;  ubuf[bo + wo2 + 4096] = (_Float16)uc2;
        ubuf[bo + wo3] = (_Float16)ud1;  ubuf[bo + wo3 + 4096] = (_Float16)ud2;
        __syncthreads();   // the ONLY barrier per exchange (8 steps)

        // ---- TWO MFMA blocks (tile0 -> j1 Ys, tile1 -> j2 Ys) ----
        v4f C0a = {0.f,0.f,0.f,0.f}, C0b = {0.f,0.f,0.f,0.f};
        v4f C1a = {0.f,0.f,0.f,0.f}, C1b = {0.f,0.f,0.f,0.f};
        {
            const _Float16* pe = ubuf + bo + beven;
            const _Float16* po = ubuf + bo + bodd;
            #pragma unroll
            for (int kk = 0; kk < 8; kk += 2) {
                v8h a00 = *(const v8h*)(pe + 32 * kk);
                v8h a01 = *(const v8h*)(po + 32 * (kk + 1));
                v8h a10 = *(const v8h*)(pe + 32 * kk + 4096);
                v8h a11 = *(const v8h*)(po + 32 * (kk + 1) + 4096);
                MFMA_AV(C0a, a00, wM0[kk]);
                MFMA_AV(C1a, a10, wM0[kk]);
                MFMA_AV(C0b, a01, wM0[kk + 1]);
                MFMA_AV(C1b, a11, wM0[kk + 1]);
            }
        }
        // no second barrier: next exchange writes the OTHER buffer (R24).

        // ---- combos, 2 butterflies, EXACT 8-step advance ----
        v4f C0 = C0a + C0b, C1 = C1a + C1b;
        float Y11 = C0[0], Y21 = C0[1], Y31 = C0[2], Y41 = C0[3];
        float Y12 = C1[0], Y22 = C1[1], Y32 = C1[2], Y42 = C1[3];
        float tA1 = Y21 + Y31, A1 = Y11 + tA1, B1 = A1 + tA1 + Y41;
        float tA2 = Y22 + Y32, A2 = Y12 + tA2, B2 = A2 + tA2 + Y42;
        float Bs = B1 + B2;
        float V = __builtin_fmaf(w3q, Bs, A1 + A2);
        V = __builtin_fmaf(4.f, B1, V);        // (7-j1)B1+(3-q)B2+A1+A2
        float SB = bfly4(Bs);
        float SV = bfly4(V);

        z1 = __builtin_fmaf(K8dt, P, z1);      // z += 8dt*P (old P)
        z1 = __builtin_fmaf(-dtdt6, SV, z1);
        P  = __builtin_fmaf(-dt6, SB, P);

        SBp = SB;  SVp = SV;                   // lag sums
        Y1L1 = Y11; Y2L1 = Y21; Y1L2 = Y12; Y2L2 = Y22;

        // ---- S partials: steps n1 = 8e+quad, n2 = n1+4 ----
        float tv1 = ub1 + uc1, sp1 = __builtin_fmaf(2.f, tv1, ua1 + ud1);
        float sq1 = ua1 + tv1;
        float tv2 = ub2 + uc2, sp2 = __builtin_fmaf(2.f, tv2, ua2 + ud2);
        float sq2 = ua2 + tv2;
        S1p += sp1 + sp2;
        S23p = __builtin_fmaf(cn, sp1, S23p) + sq1;
        S23p = __builtin_fmaf(cn - 4.f, sp2, S23p) + sq2;
        cn -= 8.f;
    }

    // ---- tail exchange: steps 96-99, buf0, tile0 only (H=4 exact) ----
    {
        float z1d = z1 + z1;
        float Pp1 = __builtin_fmaf(cPn1, SBp, P);
        float zp21 = __builtin_fmaf(Kz1a, P, z1d);
        zp21 = __builtin_fmaf(KB1, SBp, zp21);
        zp21 = __builtin_fmaf(KVn1, SVp, zp21);
        float zb21 = __builtin_fmaf(K2hdt, Pp1, zp21);
        float zc21 = __builtin_fmaf(K2hdt2n, Y1L1, zb21);
        float zd21 = __builtin_fmaf(K2dt, Pp1, zp21);
        zd21 = __builtin_fmaf(K2dthdtn, Y2L1, zd21);
        float ua1 = ueval2(zp21, w4), ub1 = ueval2(zb21, w4);
        float uc1 = ueval2(zc21, w4), ud1 = ueval2(zd21, w4);
        ubuf[wo0] = (_Float16)ua1;  ubuf[wo1] = (_Float16)ub1;
        ubuf[wo2] = (_Float16)uc1;  ubuf[wo3] = (_Float16)ud1;
        __syncthreads();

        v4f C0a = {0.f,0.f,0.f,0.f}, C0b = {0.f,0.f,0.f,0.f};
        {
            const _Float16* pe = ubuf + beven;
            const _Float16* po = ubuf + bodd;
            #pragma unroll
            for (int kk = 0; kk < 8; kk += 2) {
                v8h a00 = *(const v8h*)(pe + 32 * kk);
                v8h a01 = *(const v8h*)(po + 32 * (kk + 1));
                MFMA_AV(C0a, a00, wM0[kk]);
                MFMA_AV(C0b, a01, wM0[kk + 1]);
            }
        }
        v4f C0 = C0a + C0b;
        float Y11 = C0[0], Y21 = C0[1], Y31 = C0[2], Y41 = C0[3];
        float tA1 = Y21 + Y31, A1 = Y11 + tA1, B1 = A1 + tA1 + Y41;
        float V = __builtin_fmaf(w3q, B1, A1);   // H=4: (3-j)B + A
        float SB = bfly4(B1);
        float SV = bfly4(V);
        z1 = __builtin_fmaf(K4dt, P, z1);
        z1 = __builtin_fmaf(-dtdt6, SV, z1);
        P  = __builtin_fmaf(-dt6, SB, P);
        float tv1 = ub1 + uc1, sp1 = __builtin_fmaf(2.f, tv1, ua1 + ud1);
        float sq1 = ua1 + tv1;
        S1p += sp1;
        S23p = __builtin_fmaf(cn, sp1, S23p) + sq1;   // cn = 3-quad here
    }

    // ---- epilogue: B-frag from GLOBAL W1 (contiguous in j; L2/L3-hot;
    //      same f32->f16 conversion as staging => bit-identical) ----
    v8h wBt0[8];
    #pragma unroll
    for (int kk = 0; kk < 8; ++kk) {
        const float* wp = W1 + c0 * 256 + 32 * kk + kq;
        v4f lo = *(const v4f*)(wp);
        v4f hi = *(const v4f*)(wp + 4);
        v8h h;
        h[0] = (_Float16)lo[0]; h[1] = (_Float16)lo[1];
        h[2] = (_Float16)lo[2]; h[3] = (_Float16)lo[3];
        h[4] = (_Float16)hi[0]; h[5] = (_Float16)hi[1];
        h[6] = (_Float16)hi[2]; h[7] = (_Float16)hi[3];
        wBt0[kk] = h;
    }

    // ---- reduce S; buf0 rows {S1, S23, 0, 0}; final MFMA ----
    const float S1f  = bfly4(S1p);
    const float S23f = bfly4(S23p);
    __syncthreads();   // tail's buf0 reads done before overwrite
    if (quad == 0) {
        ubuf[0 * 256 + (c0 ^ 0)]  = (_Float16)S1f;
        ubuf[1 * 256 + (c0 ^ 8)]  = (_Float16)S23f;
        ubuf[2 * 256 + (c0 ^ 16)] = (_Float16)0.f;
        ubuf[3 * 256 + (c0 ^ 24)] = (_Float16)0.f;
    }
    __syncthreads();
    float D10, D20;
    {
        const int rowp = s & 3;
        const _Float16* ab = ubuf + rowp * 256 + 8 * (quad ^ rowp);
        v4f C0a = {0.f,0.f,0.f,0.f}, C0b = {0.f,0.f,0.f,0.f};
        #pragma unroll
        for (int kk = 0; kk < 8; kk += 2) {
            v8h a0 = *(const v8h*)(ab + 32 * kk);
            v8h a1 = *(const v8h*)(ab + 32 * (kk + 1));
            C0a = __builtin_amdgcn_mfma_f32_16x16x32_f16(a0, wBt0[kk], C0a, 0, 0, 0);
            C0b = __builtin_amdgcn_mfma_f32_16x16x32_f16(a1, wBt0[kk + 1], C0b, 0, 0, 0);
        }
        v4f C0s = C0a + C0b;
        D10 = C0s[0];  D20 = C0s[1];
    }
    const float dt6e = 0.01f / 6.f, dtdt6e = 0.01f * dt6e;
    float pT0 = p0o0 - dt6e * D10;
    float qT0 = q0o0 + 0.01f * 100.f * p0o0 - dtdt6e * D20;

    if (quad == 0)
        ((float2*)(out + (size_t)blk * 512))[c0] = make_float2(qT0, pT0);
}

extern "C" void kernel_launch(void* const* d_in, const int* in_sizes, int n_in,
                              void* d_out, int out_size, void* d_ws, size_t ws_size,
                              hipStream_t stream) {
    const float* x0 = (const float*)d_in[0];
    const float* W1 = (const float*)d_in[1];
    const float* b1 = (const float*)d_in[2];
    const float* W2 = (const float*)d_in[3];
    // d_in[4] = b2: constant offset, no effect on the gradient/dynamics.
    float* out = (float*)d_out;
    hipLaunchKernelGGL(ham_kernel, dim3(256), dim3(1024), 0, stream,
                       x0, W1, b1, W2, out);
}

// Round 8
// 99.787 us; speedup vs baseline: 1.1332x; 1.0633x over previous
//
#include <hip/hip_runtime.h>
#include <stdint.h>

// HamiltonianFlow: x [256, 8, 32, 2] (q,p); H = 0.5*sum(p^2) + MLP(q).
// dq/dt = p, dp/dt = -W u(z), z = W^T q + b1, u = (1-tanh^2(z)).*W2.
// z-space iteration with M = W^T W (R15-R23 verified).
//
// R30 = R27 (best measured: 46.3us dispatch) + BANK-OPTIMAL A-TILE SWIZZLE.
// R29c falsified the fewer-barriers thesis (59.6us): VALU/MFMA totals flat,
// barriers halved, time +29%. The budget that fits R26/R27/R29c is the
// per-CU LDS pipe: reads (16 waves x 8 b128 x ~12cyc) + conflict cycles
// (R27: 619/exchange) ~= 2.4k of the 3.6k/exchange wall. Lever: kill the
// conflicts. R27's 2-bit chunk XOR leaves read bank-slots
// v = 2(s%4) + (q^(s>>2)) covering 0..9 non-uniformly (~+4.8 cyc/read).
// Adding a 64B-granule XOR bit (row&1) gives
// v = 2(s%4) + 4(s&1) + (q^(s>>2)) mod 8: windows {0-3,6-1,4-7,2-5},
// every slot exactly 2 windows x 4 lanes = 8 lanes/slot = the 8-cycle
// conflict-free minimum (both kk parities; write instrs also disjoint).
// Implementation: odd stage-rows write col ^32; reads use even/odd-kk
// bases pe/po with a (s&1)<<5 toggle. Bit-identical math.
//
// R27 recap: 16 waves x 1 tile (1024 thr), 4-step exchange, rows
// 4*step+stage hold u-vectors, ONE barrier + ONE 8-MFMA block per 4 steps;
// quad q owns step q via horizon-4 proxy predictor {SBp, SVp} (lag-1
// exchange, err ~1e-5 stage-z, >=2 orders under f16 u-rounding floor);
// exact 4-step advance: z += 4dt*P - dtdt6*SV; P -= dt6*SB;
// SB = bfly4(B), SV = bfly4((3-q)B + A), A=Y1+Y2+Y3, B=Y1+2Y2+2Y3+Y4.
// permlane bfly4; exp-fold (2z chain) + rcp; mscr 16x320 f32 UNION ubuf.
// FULL unroll on every reg-array access (R4: dynamic index => scratch).
// Numerics: f16 storage (W, M, u, S), fp32 MFMA accum + fp32 z/P state.

typedef _Float16 v8h __attribute__((ext_vector_type(8)));
typedef float v4f __attribute__((ext_vector_type(4)));

#define NSTEPS 100
#define NEX 25    // 4 RK4 steps per exchange
#define WS 264    // wldsT row stride (f16): row = one W-COLUMN, 16B-aligned
#define US 272    // ubuf row stride, f16 (544 B == 32 mod 128)

// D(+=C) in VGPRs, A (packed-vector frag) in VGPRs, B (M-frag) from AGPRs.
#define MFMA_AV(C, A, B) \
    asm("v_mfma_f32_16x16x32_f16 %0, %1, %2, %0" : "+v"(C) : "v"(A), "a"(B))

// 4-group butterfly sum over lanes {l, l^16, l^32, l^48}, pure VALU.
__device__ __forceinline__ float bfly4(float x) {
    float a = x, b = x;
    asm("v_permlane16_swap_b32 %0, %1" : "+v"(a), "+v"(b));
    float s = a + b;
    float c = s, d = s;
    asm("v_permlane32_swap_b32 %0, %1" : "+v"(c), "+v"(d));
    return c + d;
}

// u/(4*w2) eval on pre-doubled arg zz = 2*z:  r = rcp(e^zz + 1);
// u = 4*w2*(r - r^2)  ==  (1 - tanh^2(z)) * w2  exactly in algebra.
__device__ __forceinline__ float ueval2(float zz, float w4) {
    float e_ = __expf(zz);
    float r_ = __builtin_amdgcn_rcpf(e_ + 1.f);   // vs IEEE div: ~1e-7 rel
    return w4 * __builtin_fmaf(-r_, r_, r_);
}

__global__ __launch_bounds__(1024, 4)
void ham_kernel(const float* __restrict__ x0, const float* __restrict__ W1,
                const float* __restrict__ b1, const float* __restrict__ W2,
                float* __restrict__ out)
{
    __shared__ __align__(16)  _Float16 wldsT[256 * WS];  // 135168 B: W^T (f16)
    __shared__ __align__(128) char     upool[20480];     // mscr UNION ubuf
    float*    mscr = (float*)upool;                      // setup only
    _Float16* ubuf = (_Float16*)upool;                   // 2 x 16 rows x US

    const int t = threadIdx.x;
    const int w = t >> 6;          // wave 0..15: owns tile w (16 comps)
    const int l = t & 63;
    const int quad = l >> 4;       // step-within-exchange owned by this lane
    const int s = l & 15;          // owned column / A-row
    const int c0 = 16 * w + s;     // owned component
    const int blk = blockIdx.x;
    const int sel = (s & 3) * US;  // prologue/epilogue A-row select (rows 0-3)

    // ---- stage W^T -> LDS f16: wldsT[c][r] = W[r][c] ----
    {
        const int c = t & 255;
        const int rbase = (t >> 8) * 64;   // 4 quarters x 64 rows
        #pragma unroll 1
        for (int r0 = 0; r0 < 64; r0 += 8) {
            v8h h;
            #pragma unroll
            for (int j = 0; j < 8; ++j)
                h[j] = (_Float16)W1[(rbase + r0 + j) * 256 + c];
            *(v8h*)(wldsT + c * WS + rbase + r0) = h;   // b128, one-time
        }
    }
    __syncthreads();

    // ---- wF: own-column W^T frag (B-op), contiguous b128 from wldsT ----
    v8h wF0[8];
    #pragma unroll
    for (int kk = 0; kk < 8; ++kk)
        wF0[kk] = *(const v8h*)(wldsT + c0 * WS + 32 * kk + 8 * quad);

    // ---- build M = W^T W column-block frags wM0 (B-op: M[k][c0]) ----
    v8h wM0[8];
    float* scr0 = mscr + w * 320;
    #pragma unroll
    for (int kb = 0; kb < 16; ++kb) {
        v8h aM[8];   // A[m=s][k=8quad+j] = wldsT[(16kb+s)*WS + 32kk+8quad+j]
        #pragma unroll
        for (int kk = 0; kk < 8; ++kk)
            aM[kk] = *(const v8h*)(wldsT + (16 * kb + s) * WS
                                          + 32 * kk + 8 * quad);
        v4f D0 = {0.f,0.f,0.f,0.f};
        #pragma unroll
        for (int kk = 0; kk < 8; ++kk)
            D0 = __builtin_amdgcn_mfma_f32_16x16x32_f16(aM[kk], wF0[kk], D0, 0, 0, 0);
        *(v4f*)(scr0 + s * 20 + 4 * quad) = D0;
        asm volatile("s_waitcnt lgkmcnt(0)" ::: "memory");  // in-wave x-lane
        if ((quad >> 1) == (kb & 1)) {
            #pragma unroll
            for (int j = 0; j < 8; ++j)
                wM0[kb >> 1][j] = (_Float16)scr0[s * 20 + 8 * (quad & 1) + j];
        }
        asm volatile("s_waitcnt lgkmcnt(0)" ::: "memory");
    }
    __syncthreads();   // mscr reads (all waves) done before ubuf reuse

    const float b1r0 = b1[c0];
    const float w4 = 4.f * W2[c0];
    float2 qp0 = ((const float2*)(x0 + (size_t)blk * 512))[c0];
    const float q0o0 = qp0.x, p0o0 = qp0.y;

    // ---- prologue: buf0 rows {q0, p0, 0, 0} -> z1 (C[0]), P (C[1]) ----
    if (quad == 0) {
        ubuf[c0] = (_Float16)q0o0;
        ubuf[US + c0] = (_Float16)p0o0;
        ubuf[2 * US + c0] = (_Float16)0.f;
        ubuf[3 * US + c0] = (_Float16)0.f;
    }
    __syncthreads();
    float z1, P;
    {
        const _Float16* ab = ubuf + sel + 8 * quad;
        v4f C0a = {0.f,0.f,0.f,0.f}, C0b = {0.f,0.f,0.f,0.f};
        #pragma unroll
        for (int kk = 0; kk < 8; kk += 2) {
            v8h a0 = *(const v8h*)(ab + 32 * kk);
            v8h a1 = *(const v8h*)(ab + 32 * (kk + 1));
            C0a = __builtin_amdgcn_mfma_f32_16x16x32_f16(a0, wF0[kk], C0a, 0, 0, 0);
            C0b = __builtin_amdgcn_mfma_f32_16x16x32_f16(a1, wF0[kk + 1], C0b, 0, 0, 0);
        }
        v4f C0s = C0a + C0b;
        z1 = C0s[0] + b1r0;  P = C0s[1];
    }
    __syncthreads();   // prologue reads done before u(0) overwrites buf0

    const float dt = 0.01f, hdt = 0.005f, dt6 = 0.01f / 6.f;
    const float dtdt6 = dt * dt6, hdt2 = hdt * hdt, dthdt = dt * hdt;
    const float fourdt = 4.f * dt;
    // per-quad (step j = quad) prediction coefs in {SBp, SVp} form
    // (R27-verified): Pp = P - (j/4)dt6*SBp;
    //   zp2 = 2z + 2j*dt*P + [j(4-j)dtdt6/4]*SBp - [j*dtdt6/2]*SVp
    const float qf  = (float)quad;
    const float cPn   = -(qf * 0.25f * dt6);
    const float K2cz1 = 2.f * qf * dt;
    const float K2B   = qf * (4.f - qf) * dtdt6 * 0.25f;
    const float K2Vn  = -(qf * dtdt6 * 0.5f);
    const float K2hdt = 2.f * hdt;
    const float K2hdt2n = -2.f * hdt2;
    const float K2dt  = 2.f * dt;
    const float K2dthdtn = -2.f * dthdt;
    const float wB  = 3.f - qf;          // SWB weight (3-j)

    // ---- ubuf addressing, bank-optimal swizzle f(row) = ((row>>2)&3)
    //      in the 16B-granule bits PLUS (row&1) in the 64B-granule bit ----
    // writes: row R = 4*quad+st at col (c0 ^ (quad<<3)) ^ ((st&1)<<5):
    const int cw = c0 ^ (quad << 3);
    const int R0 = 4 * quad;
    const int wo0 = (R0 + 0) * US + cw;
    const int wo1 = (R0 + 1) * US + (cw ^ 32);
    const int wo2 = (R0 + 2) * US + cw;
    const int wo3 = (R0 + 3) * US + (cw ^ 32);
    // reads: row s, logical elem 8q+32kk -> phys ^ (sx<<3) ^ ((s&1)<<5):
    // even-kk base pe, odd-kk base po (the 64B bit folds into kk parity).
    const int sx = (s >> 2) & 3;
    const int rbase = s * US + 8 * (quad ^ sx);
    const int sodd = (s & 1) << 5;
    const _Float16* pe = ubuf + rbase + sodd;          // logical even kk
    const _Float16* po = ubuf + rbase + 32 - sodd;     // logical odd  kk

    // lag state (previous exchange's sums / own-step Ys; exchange 0: zeros
    // -> benign one-time transient, R25/R27-verified class)
    float SBp = 0.f, SVp = 0.f;
    float Y1L = 0.f, Y2L = 0.f;
    float S1p = 0.f, S23p = 0.f;
    float cn = 99.f - qf;

    #pragma unroll 1
    for (int e = 0; e < NEX; ++e) {
        const int bo = (e & 1) * (16 * US);   // double-buffer offset

        // ---- predicted state for own step; 4 stage 2z's; 4 u evals ----
        float Pp  = __builtin_fmaf(cPn, SBp, P);
        float zp2 = __builtin_fmaf(K2cz1, P, z1 + z1);
        zp2 = __builtin_fmaf(K2B, SBp, zp2);
        zp2 = __builtin_fmaf(K2Vn, SVp, zp2);
        float zb2 = __builtin_fmaf(K2hdt, Pp, zp2);
        float zc2 = __builtin_fmaf(K2hdt2n, Y1L, zb2);
        float zd2 = __builtin_fmaf(K2dt, Pp, zp2);
        zd2 = __builtin_fmaf(K2dthdtn, Y2L, zd2);

        float ua = ueval2(zp2, w4);
        float ub = ueval2(zb2, w4);
        float uc = ueval2(zc2, w4);
        float ud = ueval2(zd2, w4);

        ubuf[bo + wo0] = (_Float16)ua;
        ubuf[bo + wo1] = (_Float16)ub;
        ubuf[bo + wo2] = (_Float16)uc;
        ubuf[bo + wo3] = (_Float16)ud;
        __syncthreads();   // the ONLY barrier per exchange (4 steps)

        // ---- ONE MFMA block: step-q Y1..Y4 for own comp, in-lane ----
        v4f C0s;
        {
            v4f C0a = {0.f,0.f,0.f,0.f}, C0b = {0.f,0.f,0.f,0.f};
            #pragma unroll
            for (int kk = 0; kk < 8; kk += 2) {
                v8h a0 = *(const v8h*)(pe + bo + 32 * kk);
                v8h a1 = *(const v8h*)(po + bo + 32 * kk);
                MFMA_AV(C0a, a0, wM0[kk]);
                MFMA_AV(C0b, a1, wM0[kk + 1]);
            }
            C0s = C0a + C0b;
        }
        // no second barrier: next exchange writes the OTHER buffer (R24).

        // ---- exact 4-step advance via quad-weighted butterfly sums ----
        float Y1 = C0s[0], Y2 = C0s[1], Y3 = C0s[2], Y4 = C0s[3];
        float tA = Y2 + Y3;
        float A  = Y1 + tA;                    // Y1+Y2+Y3
        float B  = A + tA + Y4;                // Y1+2Y2+2Y3+Y4
        float V  = __builtin_fmaf(wB, B, A);   // (3-j)*B + A
        float SB = bfly4(B);
        float SV = bfly4(V);                   // = SWB + SA (exact)

        z1 = __builtin_fmaf(fourdt, P, z1);    // z += 4dt*P (old P)
        z1 = __builtin_fmaf(-dtdt6, SV, z1);   //    - dt*dt6*SWB - dtdt6*SA
        P  = __builtin_fmaf(-dt6, SB, P);      // P -= dt6*SB

        SBp = SB;  SVp = SV;  Y1L = Y1;  Y2L = Y2;   // lag state

        // ---- per-lane S partials: full sp,sq for own step ----
        float tv = ub + uc;
        float sp = __builtin_fmaf(2.f, tv, ua + ud);
        float sq = ua + tv;
        S1p += sp;
        S23p = __builtin_fmaf(cn, sp, S23p) + sq;
        cn -= 4.f;
    }

    // ---- epilogue: reduce S over the 4 quads; buf0 rows {S1, S23, 0, 0} ----
    const float S1f  = bfly4(S1p);
    const float S23f = bfly4(S23p);
    __syncthreads();   // last exchange's reads (buf0, e=24) done
    if (quad == 0) {
        ubuf[c0] = (_Float16)S1f;
        ubuf[US + c0] = (_Float16)S23f;
        ubuf[2 * US + c0] = (_Float16)0.f;
        ubuf[3 * US + c0] = (_Float16)0.f;
    }
    __syncthreads();
    // wBt[kk][j] = W[c0][32kk+8quad+j] = wldsT[(32kk+8quad+j)*WS + c0]
    v8h wBt0[8];
    #pragma unroll
    for (int kk = 0; kk < 8; ++kk)
        #pragma unroll
        for (int j = 0; j < 8; ++j)
            wBt0[kk][j] = wldsT[(32 * kk + 8 * quad + j) * WS + c0];
    float D10, D20;
    {
        const _Float16* ab = ubuf + sel + 8 * quad;
        v4f C0a = {0.f,0.f,0.f,0.f}, C0b = {0.f,0.f,0.f,0.f};
        #pragma unroll
        for (int kk = 0; kk < 8; kk += 2) {
            v8h a0 = *(const v8h*)(ab + 32 * kk);
            v8h a1 = *(const v8h*)(ab + 32 * (kk + 1));
            C0a = __builtin_amdgcn_mfma_f32_16x16x32_f16(a0, wBt0[kk], C0a, 0, 0, 0);
            C0b = __builtin_amdgcn_mfma_f32_16x16x32_f16(a1, wBt0[kk + 1], C0b, 0, 0, 0);
        }
        v4f C0s = C0a + C0b;
        D10 = C0s[0];  D20 = C0s[1];
    }
    const float dt6e = 0.01f / 6.f, dtdt6e = 0.01f * dt6e;
    float pT0 = p0o0 - dt6e * D10;
    float qT0 = q0o0 + 0.01f * (float)NSTEPS * p0o0 - dtdt6e * D20;

    if (quad == 0)
        ((float2*)(out + (size_t)blk * 512))[c0] = make_float2(qT0, pT0);
}

extern "C" void kernel_launch(void* const* d_in, const int* in_sizes, int n_in,
                              void* d_out, int out_size, void* d_ws, size_t ws_size,
                              hipStream_t stream) {
    const float* x0 = (const float*)d_in[0];
    const float* W1 = (const float*)d_in[1];
    const float* b1 = (const float*)d_in[2];
    const float* W2 = (const float*)d_in[3];
    // d_in[4] = b2: constant offset, no effect on the gradient/dynamics.
    float* out = (float*)d_out;
    hipLaunchKernelGGL(ham_kernel, dim3(256), dim3(1024), 0, stream,
                       x0, W1, b1, W2, out);
}